// Round 3
// baseline (38.875 us; speedup 1.0000x reference)
//
#include <hip/hip_runtime.h>
#include <hip/hip_bf16.h>

#define SEQL 4096
#define DIM  1024
#define SEGLEN 16
#define NSEG (SEQL / SEGLEN)   // 256 segments max (worst case all tokens boundaries)
#define WCAP 256               // max backward-window boundaries (multiple of 64)
#define WEPS 1e-7f             // carry-weight underflow cutoff (threshold is 8.9e-2)

// ---------------------------------------------------------------------------
// Kernel 1: per-batch compaction. 1 block of 1024 threads per batch,
// 4 tokens/thread, wave-shuffle scan. Outputs compacted bpos/coefA/coefB, nb.
// ---------------------------------------------------------------------------
__global__ __launch_bounds__(1024) void prep_kernel(
    const float* __restrict__ prob, const int* __restrict__ mask,
    int* __restrict__ bpos, int* __restrict__ nb,
    float* __restrict__ coefA, float* __restrict__ coefB) {
  const int b = blockIdx.x;
  const int tid = threadIdx.x;
  const int wid = tid >> 6;
  const int lane = tid & 63;
  const int* mb = mask + b * SEQL;
  const float* pb = prob + b * SEQL;

  int4 m = reinterpret_cast<const int4*>(mb)[tid];
  int mv[4] = { m.x != 0, m.y != 0, m.z != 0, m.w != 0 };
  int c0 = mv[0] + mv[1] + mv[2] + mv[3];

  // wave-64 inclusive scan
  int v = c0;
#pragma unroll
  for (int off = 1; off < 64; off <<= 1) {
    int t = __shfl_up(v, off, 64);
    if (lane >= off) v += t;
  }
  __shared__ int wsum[16];
  if (lane == 63) wsum[wid] = v;
  __syncthreads();
  if (tid < 16) {
    int x = wsum[tid];
#pragma unroll
    for (int off = 1; off < 16; off <<= 1) {
      int t = __shfl_up(x, off, 64);
      if (tid >= off) x += t;
    }
    wsum[tid] = x;
  }
  __syncthreads();
  int wexcl = (wid > 0) ? wsum[wid - 1] : 0;
  int excl = wexcl + v - c0;
  int n = wsum[15];
  if (tid == 0) nb[b] = n;

  __shared__ int   bp_l[SEQL];
  __shared__ float a_l[SEQL];
  __shared__ float b_l[SEQL];
  int run = excl;
#pragma unroll
  for (int j = 0; j < 4; ++j) {
    if (mv[j]) {
      int t = tid * 4 + j;
      float pv = pb[t];
      pv = fminf(fmaxf(pv, 1e-4f), 1.0f - 1e-4f);
      bp_l[run] = t;
      a_l[run] = 1.0f - pv;
      b_l[run] = pv;
      run++;
    }
  }
  __syncthreads();
  for (int i = tid; i < n; i += 1024) {
    bpos[b * SEQL + i] = bp_l[i];
    coefA[b * SEQL + i] = a_l[i];
    coefB[b * SEQL + i] = b_l[i];
  }
}

// ---------------------------------------------------------------------------
// Kernel 2 (fused): per segment of 16 boundaries x 512 channels.
//  Phase A (wave 0): backward-window weights via shuffle prefix-product,
//    rounds of 64 boundaries, break on weight underflow. LDS: w*b, pos.
//  Phase B: carry C = sum_l wb[l] * x[pos_l]  (independent float4 loads).
//  Phase C: 16-step EMA from C + fused run-length expansion (float4 stores).
// grid = (2, NSEG, batch), block = 128 threads (each thread 4 channels).
// ---------------------------------------------------------------------------
__global__ __launch_bounds__(128) void fused_kernel(
    const float* __restrict__ h, const int* __restrict__ bpos,
    const float* __restrict__ coefA, const float* __restrict__ coefB,
    const int* __restrict__ nb, float* __restrict__ out) {
  const int b = blockIdx.z;
  const int s = blockIdx.y;
  const int n = nb[b];
  const int k0 = s * SEGLEN;
  if (k0 >= n) return;
  const int k1 = min(k0 + SEGLEN, n);
  const int tid = threadIdx.x;
  const int d0 = (blockIdx.x * 128 + tid) * 4;

  const float* hb = h + (size_t)b * SEQL * DIM;
  float* ob = out + (size_t)b * SEQL * DIM;
  const int* bp = bpos + b * SEQL;
  const float* ca = coefA + b * SEQL;
  const float* cb = coefB + b * SEQL;

  __shared__ float wb_s[WCAP];
  __shared__ int   wp_s[WCAP];
  __shared__ float sa[SEGLEN], sb[SEGLEN];
  __shared__ int   sp[SEGLEN];
  __shared__ int   wlen_s, snext_s;

  if (tid < 64) {
    // wave 0: build backward window (weights uniform across channels)
    const int lane = tid;
    int taken = 0;
    float wbase = 1.0f;
    while (taken < k0 && taken < WCAP && wbase > WEPS) {
      int navail = k0 - taken;
      int cnt = navail < 64 ? navail : 64;
      int idx = taken + lane;
      bool valid = lane < cnt;
      int j = k0 - 1 - idx;
      float a  = valid ? ca[j] : 1.0f;
      float bc = valid ? cb[j] : 0.0f;
      int pos  = valid ? bp[j] : 0;
      float prod = a;                    // inclusive prefix product over lanes
#pragma unroll
      for (int off = 1; off < 64; off <<= 1) {
        float t = __shfl_up(prod, off, 64);
        if (lane >= off) prod *= t;
      }
      float ex = __shfl_up(prod, 1, 64); // exclusive
      if (lane == 0) ex = 1.0f;
      float tot = __shfl(prod, 63, 64);
      if (valid) { wb_s[idx] = wbase * ex * bc; wp_s[idx] = pos; }
      wbase *= tot;
      taken += cnt;
    }
    if (lane == 0) wlen_s = taken;
  } else if (tid < 64 + SEGLEN) {
    int kk = tid - 64;
    int k = k0 + kk;
    if (k < n) { sa[kk] = ca[k]; sb[kk] = cb[k]; sp[kk] = bp[k]; }
  } else if (tid == 64 + SEGLEN) {
    snext_s = (k1 < n) ? bp[k1] : SEQL;
  }
  __syncthreads();

  // Phase B: carry accumulation, 4-way unrolled independent loads
  float4 C = make_float4(0.f, 0.f, 0.f, 0.f);
  const int wl = wlen_s;
  int l = 0;
  for (; l + 4 <= wl; l += 4) {
    float w0 = wb_s[l], w1 = wb_s[l+1], w2 = wb_s[l+2], w3 = wb_s[l+3];
    const float4 x0 = *(const float4*)(hb + (size_t)wp_s[l]   * DIM + d0);
    const float4 x1 = *(const float4*)(hb + (size_t)wp_s[l+1] * DIM + d0);
    const float4 x2 = *(const float4*)(hb + (size_t)wp_s[l+2] * DIM + d0);
    const float4 x3 = *(const float4*)(hb + (size_t)wp_s[l+3] * DIM + d0);
    C.x = fmaf(w0, x0.x, fmaf(w1, x1.x, fmaf(w2, x2.x, fmaf(w3, x3.x, C.x))));
    C.y = fmaf(w0, x0.y, fmaf(w1, x1.y, fmaf(w2, x2.y, fmaf(w3, x3.y, C.y))));
    C.z = fmaf(w0, x0.z, fmaf(w1, x1.z, fmaf(w2, x2.z, fmaf(w3, x3.z, C.z))));
    C.w = fmaf(w0, x0.w, fmaf(w1, x1.w, fmaf(w2, x2.w, fmaf(w3, x3.w, C.w))));
  }
  for (; l < wl; ++l) {
    float w0 = wb_s[l];
    const float4 x0 = *(const float4*)(hb + (size_t)wp_s[l] * DIM + d0);
    C.x = fmaf(w0, x0.x, C.x);
    C.y = fmaf(w0, x0.y, C.y);
    C.z = fmaf(w0, x0.z, C.z);
    C.w = fmaf(w0, x0.w, C.w);
  }

  // Phase C: in-segment EMA + run-length expansion
  float4 H = C;
  const int segn = k1 - k0;
  for (int kk = 0; kk < segn; ++kk) {
    float a = sa[kk], bc = sb[kk];
    int t = sp[kk];
    const float4 x = *(const float4*)(hb + (size_t)t * DIM + d0);
    H.x = fmaf(a, H.x, bc * x.x);
    H.y = fmaf(a, H.y, bc * x.y);
    H.z = fmaf(a, H.z, bc * x.z);
    H.w = fmaf(a, H.w, bc * x.w);
    int tn = (kk + 1 < segn) ? sp[kk + 1] : snext_s;
    for (int tt = t; tt < tn; ++tt) {
      *(float4*)(ob + (size_t)tt * DIM + d0) = H;
    }
  }
}

// ---------------------------------------------------------------------------
extern "C" void kernel_launch(void* const* d_in, const int* in_sizes, int n_in,
                              void* d_out, int out_size, void* d_ws, size_t ws_size,
                              hipStream_t stream) {
  const float* h    = (const float*)d_in[0];   // (2, 4096, 1024) f32
  const float* p    = (const float*)d_in[1];   // (2, 4096) f32
  const int*   mask = (const int*)d_in[2];     // (2, 4096) bool->int32
  float* out = (float*)d_out;                  // (2, 4096, 1024) f32

  int* bpos    = (int*)d_ws;                   // 2*4096 ints
  int* nb      = bpos + 2 * SEQL;              // 16 ints
  float* coefA = (float*)(nb + 16);            // 2*4096 f32
  float* coefB = coefA + 2 * SEQL;             // 2*4096 f32

  prep_kernel<<<dim3(2), 1024, 0, stream>>>(p, mask, bpos, nb, coefA, coefB);

  fused_kernel<<<dim3(2, NSEG, 2), 128, 0, stream>>>(h, bpos, coefA, coefB, nb, out);
}